// Round 1
// baseline (537.104 us; speedup 1.0000x reference)
//
#include <hip/hip_runtime.h>

// Problem constants (fixed by setup_inputs): B=32, L=1024, K=64, N=8
namespace {
constexpr int Bb = 32, Ll = 1024, Kk = 64, Nn = 8;
constexpr int BLK = Bb * Ll * Kk;                      // 2,097,152 (b,l,k) elements
constexpr long long HFLOATS = (long long)BLK * Nn * 2; // 33,554,432 floats in H

// Output layout (flat concatenation in reference return order)
constexpr long long OFF_VQ  = 0;                         // v_q: BLK*2
constexpr long long OFF_HQ  = (long long)BLK * 2;        // H_q: BLK*16
constexpr long long OFF_EBD = OFF_HQ + HFLOATS;          // expected_bits_demod: BLK
constexpr long long OFF_EBC = OFF_EBD + BLK;             // expected_bits_channel: BLK
constexpr long long OFF_WD  = OFF_EBC + BLK;             // w_demod: BLK*3
constexpr long long OFF_WC  = OFF_WD + (long long)BLK*3; // w_channel: BLK*3
} // namespace

__device__ __forceinline__ float lsq_fwd(float x, float s, float Qn, float Qp) {
    // forward of _lsq: round(clip(x/s, Qn, Qp)) * s   (rintf = round-half-even, matches jnp.round)
    float xs = x / s;
    float xc = fminf(fmaxf(xs, Qn), Qp);
    return rintf(xc) * s;
}

// w = hard_onehot(argmax(z)) + y - stopgrad(y), computed literally as (hard + y) - y
__device__ __forceinline__ void hard_gumbel(float z0, float z1, float z2, float w[3]) {
    int arg = 0; float m = z0;
    if (z1 > m) { m = z1; arg = 1; }   // strict > : first-occurrence tie-break, matches jnp.argmax
    if (z2 > m) { m = z2; arg = 2; }
    float e0 = expf(z0 - m), e1 = expf(z1 - m), e2 = expf(z2 - m);
    float s  = e0 + e1 + e2;
    float y0 = e0 / s, y1 = e1 / s, y2 = e2 / s;
    w[0] = ((arg == 0 ? 1.0f : 0.0f) + y0) - y0;
    w[1] = ((arg == 1 ? 1.0f : 0.0f) + y1) - y1;
    w[2] = ((arg == 2 ? 1.0f : 0.0f) + y2) - y2;
}

// ---------------------------------------------------------------------------
// Kernel 1: h_power[b,l,k] = sum_{n,c} H[b,l,n,k,c]^2  (double accumulate)
// One thread per (b,l,k). grid = BLK/256.
__global__ __launch_bounds__(256) void hpower_kernel(const float* __restrict__ H,
                                                     float* __restrict__ hp) {
    int t  = blockIdx.x * 256 + threadIdx.x;   // (bl<<6) | k
    int bl = t >> 6;
    int k  = t & 63;
    const float2* Hb = (const float2*)H + (long long)bl * (Nn * Kk) + k;
    double acc = 0.0;
    #pragma unroll
    for (int n = 0; n < Nn; ++n) {
        float2 h = Hb[n * Kk];
        float a = h.x * h.x;   // f32-rounded products (match np H*H), double sum
        float b = h.y * h.y;
        acc += (double)a;
        acc += (double)b;
    }
    hp[t] = (float)acc;
}

// ---------------------------------------------------------------------------
// Kernel 2: avg[b,k] = mean_l h_power[b,l,k]. grid = B blocks of 256.
__global__ __launch_bounds__(256) void avg_kernel(const float* __restrict__ hp,
                                                  float* __restrict__ avg) {
    int b = blockIdx.x;
    int t = threadIdx.x;
    int k = t & 63, ls = t >> 6;
    double acc = 0.0;
    for (int l = ls; l < Ll; l += 4)
        acc += (double)hp[((long long)b * Ll + l) * Kk + k];
    __shared__ double sh[256];
    sh[t] = acc;
    __syncthreads();
    if (t < 64) {
        double s = (sh[t] + sh[t + 64]) + (sh[t + 128] + sh[t + 192]);
        avg[b * Kk + t] = (float)(s * (1.0 / 1024.0));
    }
}

// ---------------------------------------------------------------------------
// Kernel 3: per-(b,l,k) MLP + gates + v_q / bits / w outputs. grid = BLK/256.
__global__ __launch_bounds__(256) void mlp_kernel(
    const float* __restrict__ v,  const float* __restrict__ snr,
    const float* __restrict__ gd, const float* __restrict__ gc,
    const float* __restrict__ W1, const float* __restrict__ b1,
    const float* __restrict__ W2, const float* __restrict__ b2,
    const float* __restrict__ Wd, const float* __restrict__ bd,
    const float* __restrict__ Wc, const float* __restrict__ bc,
    const float* __restrict__ ps2d, const float* __restrict__ ps4d,
    const float* __restrict__ hp, const float* __restrict__ avg,
    float* __restrict__ out) {
    int idx = blockIdx.x * 256 + threadIdx.x;
    int b   = idx >> 16;     // L*K = 65536
    int k   = idx & 63;

    float2 vv = ((const float2*)v)[idx];
    float p0 = vv.x, p1 = vv.y;
    float p2 = snr[idx];
    float p3 = hp[idx];
    float p4 = avg[(b << 6) | k];

    // layer 1: 5 -> 32, relu.  W1[j*32+i] uniform-indexed -> s_load broadcast.
    float h1[32];
    #pragma unroll
    for (int i = 0; i < 32; ++i) {
        float a = b1[i];
        a = fmaf(p0, W1[i],        a);
        a = fmaf(p1, W1[32 + i],   a);
        a = fmaf(p2, W1[64 + i],   a);
        a = fmaf(p3, W1[96 + i],   a);
        a = fmaf(p4, W1[128 + i],  a);
        h1[i] = fmaxf(a, 0.0f);
    }
    // layer 2: 32 -> 32, relu
    float h2[32];
    #pragma unroll
    for (int i = 0; i < 32; ++i) h2[i] = b2[i];
    #pragma unroll
    for (int j = 0; j < 32; ++j) {
        float hj = h1[j];
        #pragma unroll
        for (int i = 0; i < 32; ++i) h2[i] = fmaf(hj, W2[j * 32 + i], h2[i]);
    }
    #pragma unroll
    for (int i = 0; i < 32; ++i) h2[i] = fmaxf(h2[i], 0.0f);
    // heads: 32 -> 3 (demod) and 32 -> 3 (channel)
    float ld[3] = { bd[0], bd[1], bd[2] };
    float lc[3] = { bc[0], bc[1], bc[2] };
    #pragma unroll
    for (int j = 0; j < 32; ++j) {
        float hj = h2[j];
        ld[0] = fmaf(hj, Wd[j * 3 + 0], ld[0]);
        ld[1] = fmaf(hj, Wd[j * 3 + 1], ld[1]);
        ld[2] = fmaf(hj, Wd[j * 3 + 2], ld[2]);
        lc[0] = fmaf(hj, Wc[j * 3 + 0], lc[0]);
        lc[1] = fmaf(hj, Wc[j * 3 + 1], lc[1]);
        lc[2] = fmaf(hj, Wc[j * 3 + 2], lc[2]);
    }

    long long i3 = (long long)idx * 3;
    float wdm[3], wch[3];
    hard_gumbel(ld[0] + gd[i3], ld[1] + gd[i3 + 1], ld[2] + gd[i3 + 2], wdm);  // tau=1.0
    hard_gumbel(lc[0] + gc[i3], lc[1] + gc[i3 + 1], lc[2] + gc[i3 + 2], wch);

    float s2d = *ps2d, s4d = *ps4d;
    float q0 = wdm[1] * lsq_fwd(p0, s2d, -2.0f, 1.0f) + wdm[2] * lsq_fwd(p0, s4d, -8.0f, 7.0f);
    float q1 = wdm[1] * lsq_fwd(p1, s2d, -2.0f, 1.0f) + wdm[2] * lsq_fwd(p1, s4d, -8.0f, 7.0f);

    ((float2*)(out + OFF_VQ))[idx] = make_float2(q0, q1);
    out[OFF_EBD + idx] = wdm[1] * 4.0f + wdm[2] * 8.0f;
    out[OFF_EBC + idx] = wch[1] * 32.0f + wch[2] * 64.0f;  // 2*N*2=32, 2*N*4=64 (N=8)
    out[OFF_WD + i3 + 0] = wdm[0];
    out[OFF_WD + i3 + 1] = wdm[1];
    out[OFF_WD + i3 + 2] = wdm[2];
    out[OFF_WC + i3 + 0] = wch[0];
    out[OFF_WC + i3 + 1] = wch[1];
    out[OFF_WC + i3 + 2] = wch[2];
}

// ---------------------------------------------------------------------------
// Kernel 4: H_q = wc[1]*lsq(H,s2c,2b) + wc[2]*lsq(H,s4c,4b). One thread per float2.
__global__ __launch_bounds__(256) void hq_kernel(const float* __restrict__ H,
                                                 const float* __restrict__ wc,
                                                 const float* __restrict__ ps2c,
                                                 const float* __restrict__ ps4c,
                                                 float* __restrict__ outHQ) {
    long long t = (long long)blockIdx.x * 256 + threadIdx.x;  // pair idx: ((bl*N+n)*K + k)
    float s2c = *ps2c, s4c = *ps4c;
    float2 h = ((const float2*)H)[t];
    int k        = (int)(t & 63);
    long long bl = t >> 9;                 // (t>>6)>>3  : drop k then n
    long long wbase = ((bl << 6) | k) * 3;
    float w1 = wc[wbase + 1];
    float w2 = wc[wbase + 2];
    float q0 = w1 * lsq_fwd(h.x, s2c, -2.0f, 1.0f) + w2 * lsq_fwd(h.x, s4c, -8.0f, 7.0f);
    float q1 = w1 * lsq_fwd(h.y, s2c, -2.0f, 1.0f) + w2 * lsq_fwd(h.y, s4c, -8.0f, 7.0f);
    ((float2*)outHQ)[t] = make_float2(q0, q1);
}

// ---------------------------------------------------------------------------
extern "C" void kernel_launch(void* const* d_in, const int* in_sizes, int n_in,
                              void* d_out, int out_size, void* d_ws, size_t ws_size,
                              hipStream_t stream) {
    const float* v    = (const float*)d_in[0];
    const float* H    = (const float*)d_in[1];
    const float* snr  = (const float*)d_in[2];
    const float* gd   = (const float*)d_in[3];
    const float* gc   = (const float*)d_in[4];
    const float* W1   = (const float*)d_in[5];
    const float* b1   = (const float*)d_in[6];
    const float* W2   = (const float*)d_in[7];
    const float* b2   = (const float*)d_in[8];
    const float* Wd   = (const float*)d_in[9];
    const float* bd   = (const float*)d_in[10];
    const float* Wc   = (const float*)d_in[11];
    const float* bc   = (const float*)d_in[12];
    const float* s2d  = (const float*)d_in[13];
    const float* s4d  = (const float*)d_in[14];
    const float* s2c  = (const float*)d_in[15];
    const float* s4c  = (const float*)d_in[16];

    float* out = (float*)d_out;
    // Scratch staged inside the H_q output region (overwritten by hq_kernel last):
    float* hp  = out + OFF_HQ;        // BLK floats
    float* avg = hp + BLK;            // B*K floats

    hpower_kernel<<<BLK / 256, 256, 0, stream>>>(H, hp);
    avg_kernel<<<Bb, 256, 0, stream>>>(hp, avg);
    mlp_kernel<<<BLK / 256, 256, 0, stream>>>(v, snr, gd, gc, W1, b1, W2, b2,
                                              Wd, bd, Wc, bc, s2d, s4d, hp, avg, out);
    hq_kernel<<<(int)(HFLOATS / 2 / 256), 256, 0, stream>>>(H, out + OFF_WC, s2c, s4c,
                                                            out + OFF_HQ);
}

// Round 2
// 436.670 us; speedup vs baseline: 1.2300x; 1.2300x over previous
//
#include <hip/hip_runtime.h>

// Problem constants (fixed by setup_inputs): B=32, L=1024, K=64, N=8
namespace {
constexpr int Bb = 32, Ll = 1024, Kk = 64, Nn = 8;
constexpr int BLK = Bb * Ll * Kk;                      // 2,097,152 (b,l,k) elements
constexpr long long HFLOATS = (long long)BLK * Nn * 2; // 33,554,432 floats in H
constexpr int CH = 16;                                  // avg-reduction chunks per b
constexpr int LCH = Ll / CH;                            // 64 l's per chunk

// Output layout (flat concatenation in reference return order)
constexpr long long OFF_VQ  = 0;                         // v_q: BLK*2
constexpr long long OFF_HQ  = (long long)BLK * 2;        // H_q: BLK*16
constexpr long long OFF_EBD = OFF_HQ + HFLOATS;          // expected_bits_demod: BLK
constexpr long long OFF_EBC = OFF_EBD + BLK;             // expected_bits_channel: BLK
constexpr long long OFF_WD  = OFF_EBC + BLK;             // w_demod: BLK*3
constexpr long long OFF_WC  = OFF_WD + (long long)BLK*3; // w_channel: BLK*3
} // namespace

// forward of _lsq with precomputed reciprocal: round(clip(x*inv, Qn, Qp)) * s
// (rintf = round-half-even, matches jnp.round; inv exact for s=0.5, 1-ulp wobble
//  for s=0.1 can only move a value across a rounding boundary -> error <= s << threshold)
__device__ __forceinline__ float lsq_i(float x, float inv, float s, float Qn, float Qp) {
    float xc = fminf(fmaxf(x * inv, Qn), Qp);
    return rintf(xc) * s;
}

// w = hard_onehot(argmax(z)) + y - stopgrad(y), computed literally as (hard + y) - y
__device__ __forceinline__ void hard_gumbel(float z0, float z1, float z2, float w[3]) {
    int arg = 0; float m = z0;
    if (z1 > m) { m = z1; arg = 1; }   // strict > : first-occurrence tie-break = jnp.argmax
    if (z2 > m) { m = z2; arg = 2; }
    float e0 = expf(z0 - m), e1 = expf(z1 - m), e2 = expf(z2 - m);
    float s  = e0 + e1 + e2;
    float y0 = e0 / s, y1 = e1 / s, y2 = e2 / s;
    w[0] = ((arg == 0 ? 1.0f : 0.0f) + y0) - y0;
    w[1] = ((arg == 1 ? 1.0f : 0.0f) + y1) - y1;
    w[2] = ((arg == 2 ? 1.0f : 0.0f) + y2) - y2;
}

// ---------------------------------------------------------------------------
// Kernel 1: chunked h_power sums for avg.  partial[b][c][k] = sum_{l in chunk c}
// (f32)(sum_{n,cx} H^2)  accumulated in f64, fixed deterministic order.
// grid = Bb*CH = 512 blocks x 256 threads; block covers 64 l's x 64 k.
__global__ __launch_bounds__(256) void hpa_kernel(const float* __restrict__ H,
                                                  double* __restrict__ partial) {
    int blk = blockIdx.x;            // b*CH + c
    int b   = blk >> 4;
    int c   = blk & (CH - 1);
    int t   = threadIdx.x;
    int k   = t & 63, ls = t >> 6;   // 4 l-lanes
    const float2* Hf = (const float2*)H;
    double acc = 0.0;
    int l0 = c * LCH + ls;
    for (int i = 0; i < LCH / 4; ++i) {              // 16 l's per thread, stride 4
        int l = l0 + i * 4;
        const float2* Hb = Hf + (long long)(b * Ll + l) * (Nn * Kk) + k;
        double e = 0.0;
        #pragma unroll
        for (int n = 0; n < Nn; ++n) {
            float2 h = Hb[n * Kk];
            e += (double)(h.x * h.x);   // f32-rounded squares (match np H*H)
            e += (double)(h.y * h.y);
        }
        acc += (double)(float)e;        // hp value f32-rounded exactly as np sees it
    }
    __shared__ double sh[256];
    sh[t] = acc;
    __syncthreads();
    if (t < 64)
        partial[(long long)blk * 64 + t] =
            (sh[t] + sh[t + 64]) + (sh[t + 128] + sh[t + 192]);
}

// ---------------------------------------------------------------------------
// Kernel 2: everything else, fused. One thread per (b,l,k).
// Loads its 16 H floats once: recomputes h_power (no hp buffer), finalizes avg
// from 16 L1-resident partials, runs the MLP + gumbel gates, writes v_q, bits,
// w_demod, w_channel, and H_q from the registers already holding H.
__global__ __launch_bounds__(256) void fused_kernel(
    const float* __restrict__ v,  const float* __restrict__ snr,
    const float* __restrict__ gd, const float* __restrict__ gc,
    const float* __restrict__ W1, const float* __restrict__ b1,
    const float* __restrict__ W2, const float* __restrict__ b2,
    const float* __restrict__ Wd, const float* __restrict__ bd,
    const float* __restrict__ Wc, const float* __restrict__ bc,
    const float* __restrict__ ps2d, const float* __restrict__ ps4d,
    const float* __restrict__ ps2c, const float* __restrict__ ps4c,
    const double* __restrict__ partial,
    const float* __restrict__ H,
    float* __restrict__ out) {
    int idx = blockIdx.x * 256 + threadIdx.x;
    int b   = idx >> 16;     // L*K = 65536 (uniform per block)
    int k   = idx & 63;
    int bl  = idx >> 6;      // b*L + l

    // ---- H fragment (16 floats), reused for h_power and H_q
    const float2* Hf = (const float2*)H + (long long)bl * (Nn * Kk) + k;
    float2 hreg[Nn];
    #pragma unroll
    for (int n = 0; n < Nn; ++n) hreg[n] = Hf[n * Kk];

    // ---- h_power (identical order/rounding to R1's hpower_kernel)
    double hacc = 0.0;
    #pragma unroll
    for (int n = 0; n < Nn; ++n) {
        hacc += (double)(hreg[n].x * hreg[n].x);
        hacc += (double)(hreg[n].y * hreg[n].y);
    }
    float p3 = (float)hacc;

    // ---- avg finalize: sum 16 chunk partials (f64, fixed order), /1024
    const double* pb = partial + (long long)b * (CH * 64) + k;
    double s = 0.0;
    #pragma unroll
    for (int c = 0; c < CH; ++c) s += pb[c * 64];
    float p4 = (float)(s * (1.0 / 1024.0));

    float2 vv = ((const float2*)v)[idx];
    float p0 = vv.x, p1 = vv.y;
    float p2 = snr[idx];

    // ---- layer 1: 5 -> 32, relu (weights uniform-indexed -> scalar loads)
    float h1[32];
    #pragma unroll
    for (int i = 0; i < 32; ++i) {
        float a = b1[i];
        a = fmaf(p0, W1[i],       a);
        a = fmaf(p1, W1[32 + i],  a);
        a = fmaf(p2, W1[64 + i],  a);
        a = fmaf(p3, W1[96 + i],  a);
        a = fmaf(p4, W1[128 + i], a);
        h1[i] = fmaxf(a, 0.0f);
    }
    // ---- layer 2: 32 -> 32, relu
    float h2[32];
    #pragma unroll
    for (int i = 0; i < 32; ++i) h2[i] = b2[i];
    #pragma unroll
    for (int j = 0; j < 32; ++j) {
        float hj = h1[j];
        #pragma unroll
        for (int i = 0; i < 32; ++i) h2[i] = fmaf(hj, W2[j * 32 + i], h2[i]);
    }
    #pragma unroll
    for (int i = 0; i < 32; ++i) h2[i] = fmaxf(h2[i], 0.0f);
    // ---- heads: 32 -> 3 twice
    float ld[3] = { bd[0], bd[1], bd[2] };
    float lc[3] = { bc[0], bc[1], bc[2] };
    #pragma unroll
    for (int j = 0; j < 32; ++j) {
        float hj = h2[j];
        ld[0] = fmaf(hj, Wd[j * 3 + 0], ld[0]);
        ld[1] = fmaf(hj, Wd[j * 3 + 1], ld[1]);
        ld[2] = fmaf(hj, Wd[j * 3 + 2], ld[2]);
        lc[0] = fmaf(hj, Wc[j * 3 + 0], lc[0]);
        lc[1] = fmaf(hj, Wc[j * 3 + 1], lc[1]);
        lc[2] = fmaf(hj, Wc[j * 3 + 2], lc[2]);
    }

    long long i3 = (long long)idx * 3;
    float wdm[3], wch[3];
    hard_gumbel(ld[0] + gd[i3], ld[1] + gd[i3 + 1], ld[2] + gd[i3 + 2], wdm);  // tau=1
    hard_gumbel(lc[0] + gc[i3], lc[1] + gc[i3 + 1], lc[2] + gc[i3 + 2], wch);

    // ---- scales + reciprocals (s=0.5 reciprocal exact; s=0.1 wobble <= s)
    float s2d = *ps2d, s4d = *ps4d, s2c = *ps2c, s4c = *ps4c;
    float i2d = 1.0f / s2d, i4d = 1.0f / s4d, i2c = 1.0f / s2c, i4c = 1.0f / s4c;

    // ---- v_q
    float q0 = wdm[1] * lsq_i(p0, i2d, s2d, -2.0f, 1.0f)
             + wdm[2] * lsq_i(p0, i4d, s4d, -8.0f, 7.0f);
    float q1 = wdm[1] * lsq_i(p1, i2d, s2d, -2.0f, 1.0f)
             + wdm[2] * lsq_i(p1, i4d, s4d, -8.0f, 7.0f);
    ((float2*)(out + OFF_VQ))[idx] = make_float2(q0, q1);

    // ---- bits + gate outputs
    out[OFF_EBD + idx] = wdm[1] * 4.0f + wdm[2] * 8.0f;
    out[OFF_EBC + idx] = wch[1] * 32.0f + wch[2] * 64.0f;  // 2*N*2, 2*N*4 (N=8)
    out[OFF_WD + i3 + 0] = wdm[0];
    out[OFF_WD + i3 + 1] = wdm[1];
    out[OFF_WD + i3 + 2] = wdm[2];
    out[OFF_WC + i3 + 0] = wch[0];
    out[OFF_WC + i3 + 1] = wch[1];
    out[OFF_WC + i3 + 2] = wch[2];

    // ---- H_q from the registers already holding H
    float w1c = wch[1], w2c = wch[2];
    float2* outHQ = (float2*)(out + OFF_HQ) + (long long)bl * (Nn * Kk) + k;
    #pragma unroll
    for (int n = 0; n < Nn; ++n) {
        float hx = hreg[n].x, hy = hreg[n].y;
        float qx = w1c * lsq_i(hx, i2c, s2c, -2.0f, 1.0f)
                 + w2c * lsq_i(hx, i4c, s4c, -8.0f, 7.0f);
        float qy = w1c * lsq_i(hy, i2c, s2c, -2.0f, 1.0f)
                 + w2c * lsq_i(hy, i4c, s4c, -8.0f, 7.0f);
        outHQ[n * Kk] = make_float2(qx, qy);
    }
}

// ---------------------------------------------------------------------------
extern "C" void kernel_launch(void* const* d_in, const int* in_sizes, int n_in,
                              void* d_out, int out_size, void* d_ws, size_t ws_size,
                              hipStream_t stream) {
    const float* v    = (const float*)d_in[0];
    const float* H    = (const float*)d_in[1];
    const float* snr  = (const float*)d_in[2];
    const float* gd   = (const float*)d_in[3];
    const float* gc   = (const float*)d_in[4];
    const float* W1   = (const float*)d_in[5];
    const float* b1   = (const float*)d_in[6];
    const float* W2   = (const float*)d_in[7];
    const float* b2   = (const float*)d_in[8];
    const float* Wd   = (const float*)d_in[9];
    const float* bd   = (const float*)d_in[10];
    const float* Wc   = (const float*)d_in[11];
    const float* bc   = (const float*)d_in[12];
    const float* s2d  = (const float*)d_in[13];
    const float* s4d  = (const float*)d_in[14];
    const float* s2c  = (const float*)d_in[15];
    const float* s4c  = (const float*)d_in[16];

    float* out = (float*)d_out;
    double* partial = (double*)d_ws;   // Bb*CH*64 doubles = 256 KB, fully written by k1

    hpa_kernel<<<Bb * CH, 256, 0, stream>>>(H, partial);
    fused_kernel<<<BLK / 256, 256, 0, stream>>>(v, snr, gd, gc, W1, b1, W2, b2,
                                                Wd, bd, Wc, bc, s2d, s4d, s2c, s4c,
                                                partial, H, out);
}